// Round 4
// baseline (558.781 us; speedup 1.0000x reference)
//
#include <hip/hip_runtime.h>
#include <hip/hip_bf16.h>
#include <stdint.h>

#define SQF 0.70710678118654752f
#define SQ2 1.41421356237309505f

typedef __bf16 bf16x8 __attribute__((ext_vector_type(8)));
typedef float f32x4 __attribute__((ext_vector_type(4)));

using GLp = const __attribute__((address_space(1))) void*;
using LDp = __attribute__((address_space(3))) void*;

__device__ __forceinline__ unsigned short f2bf(float f) {
  union { float f; uint32_t u; } v; v.f = f;
  uint32_t r = v.u + 0x7fffu + ((v.u >> 16) & 1u);
  return (unsigned short)(r >> 16);
}

// ---------------- prepack conv_w -> Wp bf16 ----------------
// Layout: Wp[((ks*16 + cog)*64 + lane)*8 + e], lane=(r15 | g<<4):
//   co = cog*16 + (lane&15), ci = (ks&7)*32 + (lane>>4)*8 + e, k = ks>>3.
// A wave's A-frag (cog) at K-step ks is 64 lanes x 16B = one contiguous 1KB chunk.
__global__ void prepack_w(const float* __restrict__ w, unsigned short* __restrict__ Wp) {
  int f = blockIdx.x * 256 + threadIdx.x;
  if (f >= 40 * 8192) return;
  int e = f & 7;
  int lane = (f >> 3) & 63;
  int cog = (f >> 9) & 15;
  int ks = f >> 13;
  int co = cog * 16 + (lane & 15);
  int ci = (ks & 7) * 32 + (lane >> 4) * 8 + e;
  int k = ks >> 3;
  Wp[f] = f2bf(w[(co * 256 + ci) * 5 + k]);
}

// ---------------- transpose + cast: x[b][ci][l] f32 -> xT[b][l][ci] bf16 ----------------
__global__ void transpose_x(const float* __restrict__ x, unsigned short* __restrict__ xT) {
  __shared__ __attribute__((aligned(16))) unsigned short Ts[64 * 72];
  const int lt = blockIdx.x, ct = blockIdx.y, b = blockIdx.z;
  const int t = threadIdx.x;
  const int l0 = lt * 64, ci0 = ct * 64;
#pragma unroll
  for (int p = 0; p < 4; ++p) {
    int cil = p * 16 + (t >> 4);
    int ll = (t & 15) * 4;
    const float4 v = *(const float4*)(x + (((size_t)b * 256 + ci0 + cil) * 16384 + l0 + ll));
    Ts[(ll + 0) * 72 + cil] = f2bf(v.x);
    Ts[(ll + 1) * 72 + cil] = f2bf(v.y);
    Ts[(ll + 2) * 72 + cil] = f2bf(v.z);
    Ts[(ll + 3) * 72 + cil] = f2bf(v.w);
  }
  __syncthreads();
#pragma unroll
  for (int p = 0; p < 4; ++p) {
    int ll = p * 16 + (t >> 4);
    int cq = (t & 15) * 4;
    ushort4 v = *(const ushort4*)(&Ts[ll * 72 + cq]);
    *(ushort4*)(xT + (((size_t)b * 16384 + l0 + ll) * 256 + ci0 + cq)) = v;
  }
}

// ---------------- main conv via MFMA bf16, persistent blocks ----------------
// grid=256 blocks x 512 thr; each block processes 4 tiles (256co x 128l each).
// X double-buffered in LDS (stage t+1 under compute t); W read global->VGPR (L2-hot,
// coalesced 1KB frags, ping-pong prefetch). NO barrier inside the K-loop.
__global__ __launch_bounds__(512, 2)
void conv_mfma(const unsigned short* __restrict__ xT, const unsigned short* __restrict__ Wp,
               const float* __restrict__ bias, float* __restrict__ out) {
  __shared__ __attribute__((aligned(16))) unsigned short Xs[2][132 * 256];
  const int tid = threadIdx.x;
  const int lane = tid & 63;
  const int wv = tid >> 6;
  const int wm = wv & 3;      // co block (64 each)
  const int wn = wv >> 2;     // l block (64 each)
  const int bid = blockIdx.x;
  const int r15 = lane & 15, g = lane >> 4;

  auto stage = [&](int bufi, int tile) {
    const int lt = tile & 127, bb = tile >> 7;
    const int L0 = lt << 7;
    unsigned short* Xb = Xs[bufi];
    // zero halo rows at batch edges (rows 0,1 / 130,131)
    if (lt == 0 && tid < 64) *(float4*)(&Xb[tid * 8]) = float4{0.f, 0.f, 0.f, 0.f};
    if (lt == 127 && tid < 64) *(float4*)(&Xb[130 * 256 + tid * 8]) = float4{0.f, 0.f, 0.f, 0.f};
    const size_t xbase = (size_t)bb * 16384 * 256;
#pragma unroll
    for (int it = 0; it < 9; ++it) {
      int idx = it * 512 + tid;
      if (idx >= 132 * 32) break;          // cuts whole waves only
      int row = idx >> 5, cl = idx & 31;
      int l = L0 - 2 + row;
      void* ldst = (void*)(Xb + ((idx & ~63) << 3));   // wave-uniform base
      if (l >= 0 && l < 16384) {
        const unsigned short* src = xT + xbase + (size_t)l * 256 + ((cl ^ (row & 7)) << 3);
        __builtin_amdgcn_global_load_lds((GLp)src, (LDp)ldst, 16, 0, 0);
      }
    }
  };

  auto loadA = [&](bf16x8* a, int ks) {
#pragma unroll
    for (int mf = 0; mf < 4; ++mf)
      a[mf] = *reinterpret_cast<const bf16x8*>(
          Wp + (size_t)ks * 8192 + ((wm * 4 + mf) << 9) + (lane << 3));
  };
  auto loadB = [&](bf16x8* bv, int ks, const unsigned short* Xb) {
    const int k = ks >> 3, cb = ks & 7;
    const int c = cb * 4 + g;
    const int jb = wn * 64 + r15 + k;
#pragma unroll
    for (int nf = 0; nf < 4; ++nf) {
      int j = jb + nf * 16;
      bv[nf] = *reinterpret_cast<const bf16x8*>(&Xb[j * 256 + ((c ^ (j & 7)) << 3)]);
    }
  };

  stage(0, bid);   // tile 0 = bid

  for (int i = 0; i < 4; ++i) {
    const int tile = i * 256 + bid;
    __syncthreads();                        // drains stage(i) (vmcnt0+lgkmcnt0+barrier)
    if (i < 3) stage((i + 1) & 1, (i + 1) * 256 + bid);   // overlap under compute

    const unsigned short* Xb = Xs[i & 1];
    f32x4 acc[4][4];
#pragma unroll
    for (int mf = 0; mf < 4; ++mf)
#pragma unroll
      for (int nf = 0; nf < 4; ++nf) acc[mf][nf] = f32x4{0.f, 0.f, 0.f, 0.f};

    bf16x8 a0[4], b0[4], a1[4], b1[4];
    loadA(a0, 0); loadB(b0, 0, Xb);
    for (int ks = 0; ks < 40; ks += 2) {
      loadA(a1, ks + 1); loadB(b1, ks + 1, Xb);
#pragma unroll
      for (int mf = 0; mf < 4; ++mf)
#pragma unroll
        for (int nf = 0; nf < 4; ++nf)
          acc[mf][nf] = __builtin_amdgcn_mfma_f32_16x16x32_bf16(a0[mf], b0[nf], acc[mf][nf], 0, 0, 0);
      if (ks < 38) { loadA(a0, ks + 2); loadB(b0, ks + 2, Xb); }
#pragma unroll
      for (int mf = 0; mf < 4; ++mf)
#pragma unroll
        for (int nf = 0; nf < 4; ++nf)
          acc[mf][nf] = __builtin_amdgcn_mfma_f32_16x16x32_bf16(a1[mf], b1[nf], acc[mf][nf], 0, 0, 0);
    }

    // epilogue: D frag col(l)=lane&15, row(co)=(lane>>4)*4+reg  [m89-verified layout]
    const int lt = tile & 127, bb = tile >> 7;
    const size_t ob = (size_t)bb * 256 * 16384;
    const int lglob = (lt << 7) + wn * 64 + r15;
#pragma unroll
    for (int mf = 0; mf < 4; ++mf) {
      int co0 = wm * 64 + mf * 16 + g * 4;
#pragma unroll
      for (int r = 0; r < 4; ++r) {
        float bv = bias[co0 + r];
#pragma unroll
        for (int nf = 0; nf < 4; ++nf)
          out[ob + (size_t)(co0 + r) * 16384 + lglob + nf * 16] = acc[mf][nf][r] + bv;
      }
    }
  }
}

// ---------------- fallback naive conv (only if ws too small) ----------------
__global__ void conv_naive(const float* __restrict__ x, const float* __restrict__ w,
                           const float* __restrict__ bias, float* __restrict__ out) {
  int l = blockIdx.x * 256 + threadIdx.x;
  int co = blockIdx.y, b = blockIdx.z;
  float acc = bias[co];
  const float* xb = x + (size_t)b * 256 * 16384;
  const float* wr = w + (size_t)co * 256 * 5;
  for (int ci = 0; ci < 256; ++ci) {
    const float* xc = xb + (size_t)ci * 16384;
    const float* wc = wr + ci * 5;
#pragma unroll
    for (int k = 0; k < 5; ++k) {
      int j = l + k - 2;
      float v = (j >= 0 && j < 16384) ? xc[j] : 0.f;
      acc += wc[k] * v;
    }
  }
  out[((size_t)b * 256 + co) * 16384 + l] = acc;
}

// ---------------- fused wavelet path: out += scale * rec ----------------
#define OFF_D1  0
#define OFF_D2  8192
#define OFF_R1  12288
#define OFF_A3  16384
#define OFF_D3  18432
#define OFF_R2O 16384

__device__ __forceinline__ float conv5(const float* a, const float* w, int idx, int len) {
  if (idx >= len) return 0.f;
  float s = 0.f;
#pragma unroll
  for (int t = 0; t < 5; ++t) {
    int j = idx + t - 2;
    float v = (j >= 0 && j < len) ? a[j] : 0.f;
    s += w[t] * v;
  }
  return s;
}

__global__ __launch_bounds__(512, 2)
void wavelet_add(const float* __restrict__ x, const float* __restrict__ w0g,
                 const float* __restrict__ w1g, const float* __restrict__ w2g,
                 const float* __restrict__ scale, float* __restrict__ out) {
  __shared__ __attribute__((aligned(16))) float S[20480];
  const int t = threadIdx.x;
  const int bc = blockIdx.x;
  const int c = bc & 255;
  const size_t rowbase = (size_t)bc * 16384;
  float w0[5], w1[5], w2[5];
#pragma unroll
  for (int i = 0; i < 5; ++i) { w0[i] = w0g[c * 5 + i]; w1[i] = w1g[c * 5 + i]; w2[i] = w2g[c * 5 + i]; }
  const float sc = scale[c];

  // ---- P1: fused 3-level Haar analysis straight from global x
  {
    const float4* x4 = (const float4*)(x + rowbase);
#pragma unroll
    for (int s = 0; s < 4; ++s) {
      int i = s * 512 + t;                 // i in [0,2048)
      float4 u = x4[2 * i];
      float4 v = x4[2 * i + 1];
      float a10 = SQF * (u.x + u.y), d10 = SQF * (u.x - u.y);
      float a11 = SQF * (u.z + u.w), d11 = SQF * (u.z - u.w);
      float a12 = SQF * (v.x + v.y), d12 = SQF * (v.x - v.y);
      float a13 = SQF * (v.z + v.w), d13 = SQF * (v.z - v.w);
      *(float4*)(&S[OFF_D1 + 4 * i]) = float4{d10, d11, d12, d13};
      float a20 = SQF * (a10 + a11), d20 = SQF * (a10 - a11);
      float a21 = SQF * (a12 + a13), d21 = SQF * (a12 - a13);
      *(float2*)(&S[OFF_D2 + 2 * i]) = float2{d20, d21};
      S[OFF_A3 + i] = SQF * (a20 + a21);
      S[OFF_D3 + i] = SQF * (a20 - a21);
    }
  }
  __syncthreads();
  // ---- P2: rec1 = idwt(A3, conv5(D3,w0))
  {
    const float* A3 = &S[OFF_A3]; const float* D3 = &S[OFF_D3];
#pragma unroll
    for (int s = 0; s < 4; ++s) {
      int i = s * 512 + t;
      float a3 = A3[i];
      float a3p = (i < 2047) ? A3[i + 1] : 0.f;
      float dc = conv5(D3, w0, i, 2048);
      float dcp = conv5(D3, w0, i + 1, 2048);
      *(float2*)(&S[OFF_R1 + 2 * i]) = float2{SQ2 * a3, SQF * (a3 + a3p + dc - dcp)};
    }
  }
  __syncthreads();
  // ---- P3: rec2 odd samples only
  {
    const float* R1 = &S[OFF_R1]; const float* D2 = &S[OFF_D2];
#pragma unroll
    for (int s = 0; s < 8; ++s) {
      int i = s * 512 + t;
      float r1 = R1[i];
      float r1p = (i < 4095) ? R1[i + 1] : 0.f;
      float dm = conv5(D2, w1, i, 4096);
      float dmp = conv5(D2, w1, i + 1, 4096);
      S[OFF_R2O + i] = SQF * (r1 + r1p + dm - dmp);
    }
  }
  __syncthreads();
  // ---- P4: rec3 streamed to out (float4 RMW)
  {
    const float* R1 = &S[OFF_R1]; const float* R2O = &S[OFF_R2O]; const float* D1 = &S[OFF_D1];
    float4* op = (float4*)(out + rowbase);
#pragma unroll
    for (int s = 0; s < 8; ++s) {
      int m = s * 512 + t;
      float r1 = R1[m];
      float r1p = (m < 4095) ? R1[m + 1] : 0.f;
      float ro = R2O[m];
      float e0 = SQ2 * r1;
      float e1 = SQ2 * r1p;
      float df0 = conv5(D1, w2, 2 * m, 8192);
      float df1 = conv5(D1, w2, 2 * m + 1, 8192);
      float df2 = conv5(D1, w2, 2 * m + 2, 8192);
      float4 cu = op[m];
      cu.x += sc * (SQ2 * e0);
      cu.y += sc * (SQF * (e0 + ro + df0 - df1));
      cu.z += sc * (SQ2 * ro);
      cu.w += sc * (SQF * (ro + e1 + df1 - df2));
      op[m] = cu;
    }
  }
}

extern "C" void kernel_launch(void* const* d_in, const int* in_sizes, int n_in,
                              void* d_out, int out_size, void* d_ws, size_t ws_size,
                              hipStream_t stream) {
  const float* x = (const float*)d_in[0];
  const float* conv_w = (const float*)d_in[1];
  const float* conv_b = (const float*)d_in[2];
  const float* w0 = (const float*)d_in[3];
  const float* w1 = (const float*)d_in[4];
  const float* w2 = (const float*)d_in[5];
  const float* scale = (const float*)d_in[6];
  float* out = (float*)d_out;

  const size_t XT_BYTES = 67108864ull;           // 8*16384*256 bf16
  const size_t WP_BYTES = 655360ull;             // 40*8192 bf16
  if (ws_size >= XT_BYTES + WP_BYTES) {
    unsigned short* xT = (unsigned short*)d_ws;
    unsigned short* Wp = (unsigned short*)((char*)d_ws + XT_BYTES);
    prepack_w<<<dim3(1280), dim3(256), 0, stream>>>(conv_w, Wp);
    transpose_x<<<dim3(256, 4, 8), dim3(256), 0, stream>>>(x, xT);
    conv_mfma<<<dim3(256), dim3(512), 0, stream>>>(xT, Wp, conv_b, out);
  } else {
    conv_naive<<<dim3(64, 256, 8), dim3(256), 0, stream>>>(x, conv_w, conv_b, out);
  }
  wavelet_add<<<dim3(2048), dim3(512), 0, stream>>>(x, w0, w1, w2, scale, out);
}

// Round 5
// 184.451 us; speedup vs baseline: 3.0294x; 3.0294x over previous
//
#include <hip/hip_runtime.h>
#include <hip/hip_bf16.h>
#include <stdint.h>

#define SQF 0.70710678118654752f
#define SQ2 1.41421356237309505f

typedef __bf16 bf16x8 __attribute__((ext_vector_type(8)));
typedef float f32x4 __attribute__((ext_vector_type(4)));

using GLp = const __attribute__((address_space(1))) void*;
using LDp = __attribute__((address_space(3))) void*;

__device__ __forceinline__ unsigned short f2bf(float f) {
  union { float f; uint32_t u; } v; v.f = f;
  uint32_t r = v.u + 0x7fffu + ((v.u >> 16) & 1u);
  return (unsigned short)(r >> 16);
}

// ---------------- prepack conv_w -> Wp bf16 ----------------
// Layout: Wp[((ks*16 + cog)*64 + lane)*8 + e]:
//   co = cog*16 + (lane&15), ci = (ks&7)*32 + (lane>>4)*8 + e, k = ks>>3.
// A wave's A-frag (cog) at K-step ks is one contiguous, coalesced 1KB chunk.
__global__ void prepack_w(const float* __restrict__ w, unsigned short* __restrict__ Wp) {
  int f = blockIdx.x * 256 + threadIdx.x;
  if (f >= 40 * 8192) return;
  int e = f & 7;
  int lane = (f >> 3) & 63;
  int cog = (f >> 9) & 15;
  int ks = f >> 13;
  int co = cog * 16 + (lane & 15);
  int ci = (ks & 7) * 32 + (lane >> 4) * 8 + e;
  int k = ks >> 3;
  Wp[f] = f2bf(w[(co * 256 + ci) * 5 + k]);
}

// ---------------- transpose + cast: x[b][ci][l] f32 -> xT[b][l][ci] bf16 ----------------
__global__ void transpose_x(const float* __restrict__ x, unsigned short* __restrict__ xT) {
  __shared__ __attribute__((aligned(16))) unsigned short Ts[64 * 72];
  const int lt = blockIdx.x, ct = blockIdx.y, b = blockIdx.z;
  const int t = threadIdx.x;
  const int l0 = lt * 64, ci0 = ct * 64;
#pragma unroll
  for (int p = 0; p < 4; ++p) {
    int cil = p * 16 + (t >> 4);
    int ll = (t & 15) * 4;
    const float4 v = *(const float4*)(x + (((size_t)b * 256 + ci0 + cil) * 16384 + l0 + ll));
    Ts[(ll + 0) * 72 + cil] = f2bf(v.x);
    Ts[(ll + 1) * 72 + cil] = f2bf(v.y);
    Ts[(ll + 2) * 72 + cil] = f2bf(v.z);
    Ts[(ll + 3) * 72 + cil] = f2bf(v.w);
  }
  __syncthreads();
#pragma unroll
  for (int p = 0; p < 4; ++p) {
    int ll = p * 16 + (t >> 4);
    int cq = (t & 15) * 4;
    ushort4 v = *(const ushort4*)(&Ts[ll * 72 + cq]);
    *(ushort4*)(xT + (((size_t)b * 16384 + l0 + ll) * 256 + ci0 + cq)) = v;
  }
}

// ---------------- main conv via MFMA bf16 ----------------
// tile: 256 co x 128 l, 8 waves (4 co-groups x 2 l-groups), each wave 64x64.
// LDS = X tile only (67.6 KB -> 2 blocks/CU). W read global->VGPR (L2-hot,
// coalesced 1KB frags, unroll-2 ping-pong). NO barrier inside the K-loop.
__global__ __launch_bounds__(512, 4)
void conv_mfma(const unsigned short* __restrict__ xT, const unsigned short* __restrict__ Wp,
               const float* __restrict__ bias, float* __restrict__ out) {
  __shared__ __attribute__((aligned(16))) unsigned short Xs[132 * 256];
  const int tid = threadIdx.x;
  const int lane = tid & 63;
  const int wv = tid >> 6;
  const int wm = wv & 3;      // co block (64 each)
  const int wn = wv >> 2;     // l block (64 each)
  const int lt = blockIdx.x;  // 128 l-tiles
  const int b = blockIdx.y;
  const int l0 = lt << 7;
  const int r15 = lane & 15, g = lane >> 4;

  // zero halo rows at batch edges (rows 0,1 / 130,131)
  if (lt == 0 && tid < 64) *(float4*)(&Xs[tid * 8]) = float4{0.f, 0.f, 0.f, 0.f};
  if (lt == 127 && tid < 64) *(float4*)(&Xs[130 * 256 + tid * 8]) = float4{0.f, 0.f, 0.f, 0.f};

  // stage X tile: 132 rows x 512B, global_load_lds 16B, source-swizzled so LDS stays linear
  {
    const size_t xbase = (size_t)b * 16384 * 256;
#pragma unroll
    for (int it = 0; it < 9; ++it) {
      int idx = it * 512 + tid;
      if (idx >= 132 * 32) break;          // cuts whole waves only
      int row = idx >> 5, cl = idx & 31;
      int l = l0 - 2 + row;
      void* ldst = (void*)(Xs + ((idx & ~63) << 3));   // wave-uniform base
      if (l >= 0 && l < 16384) {
        const unsigned short* src = xT + xbase + (size_t)l * 256 + ((cl ^ (row & 7)) << 3);
        __builtin_amdgcn_global_load_lds((GLp)src, (LDp)ldst, 16, 0, 0);
      }
    }
  }

  auto loadA = [&](bf16x8* a, int ks) {
#pragma unroll
    for (int mf = 0; mf < 4; ++mf)
      a[mf] = *reinterpret_cast<const bf16x8*>(
          Wp + (size_t)ks * 8192 + ((wm * 4 + mf) << 9) + (lane << 3));
  };
  auto loadB = [&](bf16x8* bv, int ks) {
    const int k = ks >> 3, cb = ks & 7;
    const int c = cb * 4 + g;
    const int jb = wn * 64 + r15 + k;
#pragma unroll
    for (int nf = 0; nf < 4; ++nf) {
      int j = jb + nf * 16;
      bv[nf] = *reinterpret_cast<const bf16x8*>(&Xs[j * 256 + ((c ^ (j & 7)) << 3)]);
    }
  };

  f32x4 acc[4][4];
#pragma unroll
  for (int mf = 0; mf < 4; ++mf)
#pragma unroll
    for (int nf = 0; nf < 4; ++nf) acc[mf][nf] = f32x4{0.f, 0.f, 0.f, 0.f};

  bf16x8 aA[4], aB[4], bfr[4];
  loadA(aA, 0);                 // A prefetch rides over the staging barrier
  __syncthreads();              // X tile resident

  for (int ks = 0; ks < 40; ks += 2) {
    loadA(aB, ks + 1);          // prefetch next A while computing with aA
    loadB(bfr, ks);
#pragma unroll
    for (int mf = 0; mf < 4; ++mf)
#pragma unroll
      for (int nf = 0; nf < 4; ++nf)
        acc[mf][nf] = __builtin_amdgcn_mfma_f32_16x16x32_bf16(aA[mf], bfr[nf], acc[mf][nf], 0, 0, 0);
    if (ks < 38) loadA(aA, ks + 2);
    loadB(bfr, ks + 1);
#pragma unroll
    for (int mf = 0; mf < 4; ++mf)
#pragma unroll
      for (int nf = 0; nf < 4; ++nf)
        acc[mf][nf] = __builtin_amdgcn_mfma_f32_16x16x32_bf16(aB[mf], bfr[nf], acc[mf][nf], 0, 0, 0);
  }

  // epilogue: D frag col(l)=lane&15, row(co)=(lane>>4)*4+reg  [m89-verified layout]
  const size_t ob = (size_t)b * 256 * 16384;
  const int lglob = l0 + wn * 64 + r15;
#pragma unroll
  for (int mf = 0; mf < 4; ++mf) {
    int co0 = wm * 64 + mf * 16 + g * 4;
#pragma unroll
    for (int r = 0; r < 4; ++r) {
      float bv = bias[co0 + r];
#pragma unroll
      for (int nf = 0; nf < 4; ++nf)
        out[ob + (size_t)(co0 + r) * 16384 + lglob + nf * 16] = acc[mf][nf][r] + bv;
    }
  }
}

// ---------------- fallback naive conv (only if ws too small) ----------------
__global__ void conv_naive(const float* __restrict__ x, const float* __restrict__ w,
                           const float* __restrict__ bias, float* __restrict__ out) {
  int l = blockIdx.x * 256 + threadIdx.x;
  int co = blockIdx.y, b = blockIdx.z;
  float acc = bias[co];
  const float* xb = x + (size_t)b * 256 * 16384;
  const float* wr = w + (size_t)co * 256 * 5;
  for (int ci = 0; ci < 256; ++ci) {
    const float* xc = xb + (size_t)ci * 16384;
    const float* wc = wr + ci * 5;
#pragma unroll
    for (int k = 0; k < 5; ++k) {
      int j = l + k - 2;
      float v = (j >= 0 && j < 16384) ? xc[j] : 0.f;
      acc += wc[k] * v;
    }
  }
  out[((size_t)b * 256 + co) * 16384 + l] = acc;
}

// ---------------- fused wavelet path: out += scale * rec ----------------
#define OFF_D1  0
#define OFF_D2  8192
#define OFF_R1  12288
#define OFF_A3  16384
#define OFF_D3  18432
#define OFF_R2O 16384

__device__ __forceinline__ float conv5(const float* a, const float* w, int idx, int len) {
  if (idx >= len) return 0.f;
  float s = 0.f;
#pragma unroll
  for (int t = 0; t < 5; ++t) {
    int j = idx + t - 2;
    float v = (j >= 0 && j < len) ? a[j] : 0.f;
    s += w[t] * v;
  }
  return s;
}

__global__ __launch_bounds__(512, 2)
void wavelet_add(const float* __restrict__ x, const float* __restrict__ w0g,
                 const float* __restrict__ w1g, const float* __restrict__ w2g,
                 const float* __restrict__ scale, float* __restrict__ out) {
  __shared__ __attribute__((aligned(16))) float S[20480];
  const int t = threadIdx.x;
  const int bc = blockIdx.x;
  const int c = bc & 255;
  const size_t rowbase = (size_t)bc * 16384;
  float w0[5], w1[5], w2[5];
#pragma unroll
  for (int i = 0; i < 5; ++i) { w0[i] = w0g[c * 5 + i]; w1[i] = w1g[c * 5 + i]; w2[i] = w2g[c * 5 + i]; }
  const float sc = scale[c];

  // ---- P1: fused 3-level Haar analysis straight from global x
  {
    const float4* x4 = (const float4*)(x + rowbase);
#pragma unroll
    for (int s = 0; s < 4; ++s) {
      int i = s * 512 + t;                 // i in [0,2048)
      float4 u = x4[2 * i];
      float4 v = x4[2 * i + 1];
      float a10 = SQF * (u.x + u.y), d10 = SQF * (u.x - u.y);
      float a11 = SQF * (u.z + u.w), d11 = SQF * (u.z - u.w);
      float a12 = SQF * (v.x + v.y), d12 = SQF * (v.x - v.y);
      float a13 = SQF * (v.z + v.w), d13 = SQF * (v.z - v.w);
      *(float4*)(&S[OFF_D1 + 4 * i]) = float4{d10, d11, d12, d13};
      float a20 = SQF * (a10 + a11), d20 = SQF * (a10 - a11);
      float a21 = SQF * (a12 + a13), d21 = SQF * (a12 - a13);
      *(float2*)(&S[OFF_D2 + 2 * i]) = float2{d20, d21};
      S[OFF_A3 + i] = SQF * (a20 + a21);
      S[OFF_D3 + i] = SQF * (a20 - a21);
    }
  }
  __syncthreads();
  // ---- P2: rec1 = idwt(A3, conv5(D3,w0))
  {
    const float* A3 = &S[OFF_A3]; const float* D3 = &S[OFF_D3];
#pragma unroll
    for (int s = 0; s < 4; ++s) {
      int i = s * 512 + t;
      float a3 = A3[i];
      float a3p = (i < 2047) ? A3[i + 1] : 0.f;
      float dc = conv5(D3, w0, i, 2048);
      float dcp = conv5(D3, w0, i + 1, 2048);
      *(float2*)(&S[OFF_R1 + 2 * i]) = float2{SQ2 * a3, SQF * (a3 + a3p + dc - dcp)};
    }
  }
  __syncthreads();
  // ---- P3: rec2 odd samples only
  {
    const float* R1 = &S[OFF_R1]; const float* D2 = &S[OFF_D2];
#pragma unroll
    for (int s = 0; s < 8; ++s) {
      int i = s * 512 + t;
      float r1 = R1[i];
      float r1p = (i < 4095) ? R1[i + 1] : 0.f;
      float dm = conv5(D2, w1, i, 4096);
      float dmp = conv5(D2, w1, i + 1, 4096);
      S[OFF_R2O + i] = SQF * (r1 + r1p + dm - dmp);
    }
  }
  __syncthreads();
  // ---- P4: rec3 streamed to out (float4 RMW)
  {
    const float* R1 = &S[OFF_R1]; const float* R2O = &S[OFF_R2O]; const float* D1 = &S[OFF_D1];
    float4* op = (float4*)(out + rowbase);
#pragma unroll
    for (int s = 0; s < 8; ++s) {
      int m = s * 512 + t;
      float r1 = R1[m];
      float r1p = (m < 4095) ? R1[m + 1] : 0.f;
      float ro = R2O[m];
      float e0 = SQ2 * r1;
      float e1 = SQ2 * r1p;
      float df0 = conv5(D1, w2, 2 * m, 8192);
      float df1 = conv5(D1, w2, 2 * m + 1, 8192);
      float df2 = conv5(D1, w2, 2 * m + 2, 8192);
      float4 cu = op[m];
      cu.x += sc * (SQ2 * e0);
      cu.y += sc * (SQF * (e0 + ro + df0 - df1));
      cu.z += sc * (SQ2 * ro);
      cu.w += sc * (SQF * (ro + e1 + df1 - df2));
      op[m] = cu;
    }
  }
}

extern "C" void kernel_launch(void* const* d_in, const int* in_sizes, int n_in,
                              void* d_out, int out_size, void* d_ws, size_t ws_size,
                              hipStream_t stream) {
  const float* x = (const float*)d_in[0];
  const float* conv_w = (const float*)d_in[1];
  const float* conv_b = (const float*)d_in[2];
  const float* w0 = (const float*)d_in[3];
  const float* w1 = (const float*)d_in[4];
  const float* w2 = (const float*)d_in[5];
  const float* scale = (const float*)d_in[6];
  float* out = (float*)d_out;

  const size_t XT_BYTES = 67108864ull;           // 8*16384*256 bf16
  const size_t WP_BYTES = 655360ull;             // 40*8192 bf16
  if (ws_size >= XT_BYTES + WP_BYTES) {
    unsigned short* xT = (unsigned short*)d_ws;
    unsigned short* Wp = (unsigned short*)((char*)d_ws + XT_BYTES);
    prepack_w<<<dim3(1280), dim3(256), 0, stream>>>(conv_w, Wp);
    transpose_x<<<dim3(256, 4, 8), dim3(256), 0, stream>>>(x, xT);
    conv_mfma<<<dim3(128, 8), dim3(512), 0, stream>>>(xT, Wp, conv_b, out);
  } else {
    conv_naive<<<dim3(64, 256, 8), dim3(256), 0, stream>>>(x, conv_w, conv_b, out);
  }
  wavelet_add<<<dim3(2048), dim3(512), 0, stream>>>(x, w0, w1, w2, scale, out);
}

// Round 6
// 179.499 us; speedup vs baseline: 3.1130x; 1.0276x over previous
//
#include <hip/hip_runtime.h>
#include <hip/hip_bf16.h>
#include <stdint.h>

#define SQF 0.70710678118654752f
#define SQ2 1.41421356237309505f

typedef __bf16 bf16x8 __attribute__((ext_vector_type(8)));
typedef float f32x4 __attribute__((ext_vector_type(4)));

__device__ __forceinline__ unsigned short f2bf(float f) {
  union { float f; uint32_t u; } v; v.f = f;
  uint32_t r = v.u + 0x7fffu + ((v.u >> 16) & 1u);
  return (unsigned short)(r >> 16);
}
__device__ __forceinline__ float bf2f(unsigned short h) {
  union { uint32_t u; float f; } v; v.u = (uint32_t)h << 16; return v.f;
}

// ---------------- prepack conv_w -> Wp bf16 ----------------
// Layout: Wp[((ks*16 + cog)*64 + lane)*8 + e]:
//   co = cog*16 + (lane&15), ci = (ks&7)*32 + (lane>>4)*8 + e, k = ks>>3.
// A wave's A-frag (cog) at K-step ks is one contiguous, coalesced 1KB chunk.
__global__ void prepack_w(const float* __restrict__ w, unsigned short* __restrict__ Wp) {
  int f = blockIdx.x * 256 + threadIdx.x;
  if (f >= 40 * 8192) return;
  int e = f & 7;
  int lane = (f >> 3) & 63;
  int cog = (f >> 9) & 15;
  int ks = f >> 13;
  int co = cog * 16 + (lane & 15);
  int ci = (ks & 7) * 32 + (lane >> 4) * 8 + e;
  int k = ks >> 3;
  Wp[f] = f2bf(w[(co * 256 + ci) * 5 + k]);
}

// ---------------- main conv via MFMA bf16, fused transpose staging ----------------
// tile: 256 co x 128 l, 8 waves (4 co-groups x 2 l-groups), each wave 64x64.
// Staging reads x [b][ci][l] f32 directly (coalesced along l), casts to bf16, and
// ds_writes into the XOR-slot-swizzled [row j][256 ci] layout (same involution as reads).
// LDS = X tile only (66 KB -> 2 blocks/CU). W global->VGPR (L2-hot 1KB frags, ping-pong).
// NO barrier inside the K-loop.
__global__ __launch_bounds__(512, 4)
void conv_mfma(const float* __restrict__ x, const unsigned short* __restrict__ Wp,
               const float* __restrict__ bias, float* __restrict__ out) {
  __shared__ __attribute__((aligned(16))) unsigned short Xs[132 * 256];
  const int tid = threadIdx.x;
  const int lane = tid & 63;
  const int wv = tid >> 6;
  const int wm = wv & 3;      // co block (64 each)
  const int wn = wv >> 2;     // l block (64 each)
  const int lt = blockIdx.x;  // 128 l-tiles
  const int b = blockIdx.y;
  const int l0 = lt << 7;
  const int r15 = lane & 15, g = lane >> 4;

  // ---- fused transpose+cast staging: rows j=0..131 (l = l0-2+j), all 256 ci
  {
    const int tl = tid & 127;        // row within rep
    const int cg = tid >> 7;         // 64-ci quarter
    const float* xb = x + (size_t)b * 256 * 16384;
#pragma unroll
    for (int rep = 0; rep < 2; ++rep) {
      int j = rep * 128 + tl;
      if (j >= 132) break;           // rep1: only tl<4 active
      int l = l0 - 2 + j;
      bool inb = (l >= 0 && l < 16384);
      const float* xl = xb + l;
#pragma unroll
      for (int i8 = 0; i8 < 16; ++i8) {
        int ci = cg * 64 + i8 * 4;
        float v0 = 0.f, v1 = 0.f, v2 = 0.f, v3 = 0.f;
        if (inb) {
          v0 = xl[(size_t)(ci + 0) * 16384];
          v1 = xl[(size_t)(ci + 1) * 16384];
          v2 = xl[(size_t)(ci + 2) * 16384];
          v3 = xl[(size_t)(ci + 3) * 16384];
        }
        uint32_t p0 = ((uint32_t)f2bf(v1) << 16) | f2bf(v0);
        uint32_t p1 = ((uint32_t)f2bf(v3) << 16) | f2bf(v2);
        int slot = (ci >> 3) ^ (j & 7);                       // same involution as read side
        int byteoff = j * 512 + (slot << 4) + (ci & 7) * 2;   // (ci&7) in {0,4}
        *(uint2*)((char*)Xs + byteoff) = uint2{p0, p1};
      }
    }
  }

  auto loadA = [&](bf16x8* a, int ks) {
#pragma unroll
    for (int mf = 0; mf < 4; ++mf)
      a[mf] = *reinterpret_cast<const bf16x8*>(
          Wp + (size_t)ks * 8192 + ((wm * 4 + mf) << 9) + (lane << 3));
  };
  auto loadB = [&](bf16x8* bv, int ks) {
    const int k = ks >> 3, cb = ks & 7;
    const int c = cb * 4 + g;
    const int jb = wn * 64 + r15 + k;
#pragma unroll
    for (int nf = 0; nf < 4; ++nf) {
      int j = jb + nf * 16;
      bv[nf] = *reinterpret_cast<const bf16x8*>(&Xs[j * 256 + ((c ^ (j & 7)) << 3)]);
    }
  };

  f32x4 acc[4][4];
#pragma unroll
  for (int mf = 0; mf < 4; ++mf)
#pragma unroll
    for (int nf = 0; nf < 4; ++nf) acc[mf][nf] = f32x4{0.f, 0.f, 0.f, 0.f};

  bf16x8 aA[4], aB[4], bfr[4];
  loadA(aA, 0);                 // A prefetch rides over the staging barrier
  __syncthreads();              // X tile resident (drains ds_writes)

  for (int ks = 0; ks < 40; ks += 2) {
    loadA(aB, ks + 1);          // prefetch next A while computing with aA
    loadB(bfr, ks);
#pragma unroll
    for (int mf = 0; mf < 4; ++mf)
#pragma unroll
      for (int nf = 0; nf < 4; ++nf)
        acc[mf][nf] = __builtin_amdgcn_mfma_f32_16x16x32_bf16(aA[mf], bfr[nf], acc[mf][nf], 0, 0, 0);
    if (ks < 38) loadA(aA, ks + 2);
    loadB(bfr, ks + 1);
#pragma unroll
    for (int mf = 0; mf < 4; ++mf)
#pragma unroll
      for (int nf = 0; nf < 4; ++nf)
        acc[mf][nf] = __builtin_amdgcn_mfma_f32_16x16x32_bf16(aB[mf], bfr[nf], acc[mf][nf], 0, 0, 0);
  }

  // epilogue: D frag col(l)=lane&15, row(co)=(lane>>4)*4+reg  [m89-verified layout]
  const size_t ob = (size_t)b * 256 * 16384;
  const int lglob = l0 + wn * 64 + r15;
#pragma unroll
  for (int mf = 0; mf < 4; ++mf) {
    int co0 = wm * 64 + mf * 16 + g * 4;
#pragma unroll
    for (int r = 0; r < 4; ++r) {
      float bv = bias[co0 + r];
#pragma unroll
      for (int nf = 0; nf < 4; ++nf)
        out[ob + (size_t)(co0 + r) * 16384 + lglob + nf * 16] = acc[mf][nf][r] + bv;
    }
  }
}

// ---------------- fallback naive conv (only if ws too small) ----------------
__global__ void conv_naive(const float* __restrict__ x, const float* __restrict__ w,
                           const float* __restrict__ bias, float* __restrict__ out) {
  int l = blockIdx.x * 256 + threadIdx.x;
  int co = blockIdx.y, b = blockIdx.z;
  float acc = bias[co];
  const float* xb = x + (size_t)b * 256 * 16384;
  const float* wr = w + (size_t)co * 256 * 5;
  for (int ci = 0; ci < 256; ++ci) {
    const float* xc = xb + (size_t)ci * 16384;
    const float* wc = wr + ci * 5;
#pragma unroll
    for (int k = 0; k < 5; ++k) {
      int j = l + k - 2;
      float v = (j >= 0 && j < 16384) ? xc[j] : 0.f;
      acc += wc[k] * v;
    }
  }
  out[((size_t)b * 256 + co) * 16384 + l] = acc;
}

// ---------------- fused wavelet path: out += scale * rec ----------------
// LDS: D1h bf16[8192] (16KB) + S f32: D2[0,4096) R1[4096,8192) A3[8192,10240)
// D3[10240,12288), R2O overlays A3|D3. Total exactly 64 KB -> 2 blocks/CU.
#define OFF_D2  0
#define OFF_R1  4096
#define OFF_A3  8192
#define OFF_D3  10240
#define OFF_R2O 8192

__device__ __forceinline__ float conv5(const float* a, const float* w, int idx, int len) {
  if (idx >= len) return 0.f;
  float s = 0.f;
#pragma unroll
  for (int t = 0; t < 5; ++t) {
    int j = idx + t - 2;
    float v = (j >= 0 && j < len) ? a[j] : 0.f;
    s += w[t] * v;
  }
  return s;
}
__device__ __forceinline__ float conv5h(const unsigned short* a, const float* w, int idx, int len) {
  if (idx >= len) return 0.f;
  float s = 0.f;
#pragma unroll
  for (int t = 0; t < 5; ++t) {
    int j = idx + t - 2;
    float v = (j >= 0 && j < len) ? bf2f(a[j]) : 0.f;
    s += w[t] * v;
  }
  return s;
}

__global__ __launch_bounds__(512, 2)
void wavelet_add(const float* __restrict__ x, const float* __restrict__ w0g,
                 const float* __restrict__ w1g, const float* __restrict__ w2g,
                 const float* __restrict__ scale, float* __restrict__ out) {
  __shared__ __attribute__((aligned(16))) unsigned short D1h[8192];  // bf16 D1
  __shared__ __attribute__((aligned(16))) float S[12288];
  const int t = threadIdx.x;
  const int bc = blockIdx.x;
  const int c = bc & 255;
  const size_t rowbase = (size_t)bc * 16384;
  float w0[5], w1[5], w2[5];
#pragma unroll
  for (int i = 0; i < 5; ++i) { w0[i] = w0g[c * 5 + i]; w1[i] = w1g[c * 5 + i]; w2[i] = w2g[c * 5 + i]; }
  const float sc = scale[c];

  // ---- P1: fused 3-level Haar analysis straight from global x
  {
    const float4* x4 = (const float4*)(x + rowbase);
#pragma unroll
    for (int s = 0; s < 4; ++s) {
      int i = s * 512 + t;                 // i in [0,2048)
      float4 u = x4[2 * i];
      float4 v = x4[2 * i + 1];
      float a10 = SQF * (u.x + u.y), d10 = SQF * (u.x - u.y);
      float a11 = SQF * (u.z + u.w), d11 = SQF * (u.z - u.w);
      float a12 = SQF * (v.x + v.y), d12 = SQF * (v.x - v.y);
      float a13 = SQF * (v.z + v.w), d13 = SQF * (v.z - v.w);
      uint32_t q0 = ((uint32_t)f2bf(d11) << 16) | f2bf(d10);
      uint32_t q1 = ((uint32_t)f2bf(d13) << 16) | f2bf(d12);
      *(uint2*)(&D1h[4 * i]) = uint2{q0, q1};
      float a20 = SQF * (a10 + a11), d20 = SQF * (a10 - a11);
      float a21 = SQF * (a12 + a13), d21 = SQF * (a12 - a13);
      *(float2*)(&S[OFF_D2 + 2 * i]) = float2{d20, d21};
      S[OFF_A3 + i] = SQF * (a20 + a21);
      S[OFF_D3 + i] = SQF * (a20 - a21);
    }
  }
  __syncthreads();
  // ---- P2: rec1 = idwt(A3, conv5(D3,w0))
  {
    const float* A3 = &S[OFF_A3]; const float* D3 = &S[OFF_D3];
#pragma unroll
    for (int s = 0; s < 4; ++s) {
      int i = s * 512 + t;                 // i in [0,2048)
      float a3 = A3[i];
      float a3p = (i < 2047) ? A3[i + 1] : 0.f;
      float dc = conv5(D3, w0, i, 2048);
      float dcp = conv5(D3, w0, i + 1, 2048);
      *(float2*)(&S[OFF_R1 + 2 * i]) = float2{SQ2 * a3, SQF * (a3 + a3p + dc - dcp)};
    }
  }
  __syncthreads();
  // ---- P3: rec2 odd samples only (evens recomputed from R1); overlays A3|D3
  {
    const float* R1 = &S[OFF_R1]; const float* D2 = &S[OFF_D2];
#pragma unroll
    for (int s = 0; s < 8; ++s) {
      int i = s * 512 + t;                 // i in [0,4096)
      float r1 = R1[i];
      float r1p = (i < 4095) ? R1[i + 1] : 0.f;
      float dm = conv5(D2, w1, i, 4096);
      float dmp = conv5(D2, w1, i + 1, 4096);
      S[OFF_R2O + i] = SQF * (r1 + r1p + dm - dmp);
    }
  }
  __syncthreads();
  // ---- P4: rec3 streamed to out (float4 RMW). rec2[2m]=sqrt2*rec1[m], rec2[2m+1]=R2O[m]
  {
    const float* R1 = &S[OFF_R1]; const float* R2O = &S[OFF_R2O];
    float4* op = (float4*)(out + rowbase);
#pragma unroll
    for (int s = 0; s < 8; ++s) {
      int m = s * 512 + t;                 // m in [0,4096)
      float r1 = R1[m];
      float r1p = (m < 4095) ? R1[m + 1] : 0.f;
      float ro = R2O[m];
      float e0 = SQ2 * r1;                 // rec2[2m]
      float e1 = SQ2 * r1p;                // rec2[2m+2]
      float df0 = conv5h(D1h, w2, 2 * m, 8192);
      float df1 = conv5h(D1h, w2, 2 * m + 1, 8192);
      float df2 = conv5h(D1h, w2, 2 * m + 2, 8192);
      float4 cu = op[m];
      cu.x += sc * (SQ2 * e0);
      cu.y += sc * (SQF * (e0 + ro + df0 - df1));
      cu.z += sc * (SQ2 * ro);
      cu.w += sc * (SQF * (ro + e1 + df1 - df2));
      op[m] = cu;
    }
  }
}

extern "C" void kernel_launch(void* const* d_in, const int* in_sizes, int n_in,
                              void* d_out, int out_size, void* d_ws, size_t ws_size,
                              hipStream_t stream) {
  const float* x = (const float*)d_in[0];
  const float* conv_w = (const float*)d_in[1];
  const float* conv_b = (const float*)d_in[2];
  const float* w0 = (const float*)d_in[3];
  const float* w1 = (const float*)d_in[4];
  const float* w2 = (const float*)d_in[5];
  const float* scale = (const float*)d_in[6];
  float* out = (float*)d_out;

  const size_t WP_BYTES = 655360ull;             // 40*8192 bf16
  if (ws_size >= WP_BYTES) {
    unsigned short* Wp = (unsigned short*)d_ws;
    prepack_w<<<dim3(1280), dim3(256), 0, stream>>>(conv_w, Wp);
    conv_mfma<<<dim3(128, 8), dim3(512), 0, stream>>>(x, Wp, conv_b, out);
  } else {
    conv_naive<<<dim3(64, 256, 8), dim3(256), 0, stream>>>(x, conv_w, conv_b, out);
  }
  wavelet_add<<<dim3(2048), dim3(512), 0, stream>>>(x, w0, w1, w2, scale, out);
}